// Round 11
// baseline (204.135 us; speedup 1.0000x reference)
//
#include <hip/hip_runtime.h>

#define CAP 64
#define BCAP 2048         // entries per 128-node fine bin (mean ~1535, +13 sigma)
#define RADIX_UNITS 4096  // int2 units per radix block = 8192 edges = 16/thread

typedef short bf16x8 __attribute__((ext_vector_type(8)));
typedef float f32x4 __attribute__((ext_vector_type(4)));
typedef unsigned int u32x2 __attribute__((ext_vector_type(2)));
typedef unsigned short u16;
typedef unsigned int u32;

__device__ __forceinline__ u16 f32_to_bf16(float f) {
  u32 b = __float_as_uint(f);
  b += 0x7fffu + ((b >> 16) & 1u);  // round to nearest even
  return (u16)(b >> 16);
}

// ---------------------------------------------------------------------------
// K1: three-limb front dispatch (r10-proven).
//  [0, nradix):            atomic-free radix scatter into FINE (128-node)
//                          bins -- 2-pass structure, bin = dst>>7.
//  [nradix, nradix+nconv): X fp32 -> bf16 (Xb in d_out head).
//  [nradix+nconv, +128):   W transpose+convert into ws head.
// ---------------------------------------------------------------------------
__global__ __launch_bounds__(256) void front_kernel(
    const float* __restrict__ X, u16* __restrict__ Xb, int n8,
    const int* __restrict__ ra, const int* __restrict__ rb,
    int* __restrict__ gOff, int2* __restrict__ binned,
    const float* __restrict__ Wh, const float* __restrict__ Wo,
    u16* __restrict__ WhT, u16* __restrict__ WoT, int nedges, int nunits,
    int nbins, int nradix, int nconv) {
  const int tid = threadIdx.x;
  if ((int)blockIdx.x >= nradix + nconv) {
    // ---- convert_w path ----
    int idx = ((int)blockIdx.x - nradix - nconv) * 256 + tid;  // 0..32767
    const float* src = (idx < 16384) ? Wh : Wo;
    u16* dst = (idx < 16384) ? WhT : WoT;
    int i = idx & 16383;
    int k = i >> 7, n = i & 127;
    dst[n * 128 + k] = f32_to_bf16(src[k * 128 + n]);
    return;
  }
  if ((int)blockIdx.x >= nradix) {
    // ---- convert_x path ----
    int i = ((int)blockIdx.x - nradix) * 256 + tid;
    if (i >= n8) return;
    float4 a = ((const float4*)X)[2 * i];
    float4 b = ((const float4*)X)[2 * i + 1];
    int4 o;
    o.x = (int)((u32)f32_to_bf16(a.x) | ((u32)f32_to_bf16(a.y) << 16));
    o.y = (int)((u32)f32_to_bf16(a.z) | ((u32)f32_to_bf16(a.w) << 16));
    o.z = (int)((u32)f32_to_bf16(b.x) | ((u32)f32_to_bf16(b.y) << 16));
    o.w = (int)((u32)f32_to_bf16(b.z) | ((u32)f32_to_bf16(b.w) << 16));
    ((int4*)Xb)[i] = o;
    return;
  }
  // ---- radix scatter path (fine bins: dst>>7) ----
  __shared__ int lh[1024];  // bin histogram, then running slot position
  for (int b = tid; b < nbins; b += 256) lh[b] = 0;
  __syncthreads();
  const int u0 = (int)blockIdx.x * RADIX_UNITS;

  // scan 1: count entries per bin
  for (int k = 0; k < RADIX_UNITS / 256; ++k) {
    int u = u0 + k * 256 + tid;
    if (u < nunits) {
      long long apk = ((const long long*)ra)[u];
      long long bpk = ((const long long*)rb)[u];
      int a0 = (int)apk, a1 = (int)(apk >> 32);
      int b0 = (int)bpk, b1 = (int)(bpk >> 32);
      bool has1 = (2 * u + 1) < nedges;
      atomicAdd(&lh[a0 >> 7], 1);
      atomicAdd(&lh[b0 >> 7], 1);
      if (has1) {
        atomicAdd(&lh[a1 >> 7], 1);
        atomicAdd(&lh[b1 >> 7], 1);
      }
    }
  }
  __syncthreads();
  // reserve contiguous space per bin (one device atomic per block,bin)
  for (int b = tid; b < nbins; b += 256) {
    int c = lh[b];
    lh[b] = (c > 0) ? atomicAdd(&gOff[b], c) : 0;
  }
  __syncthreads();
  // scan 2: place (dst,src) pairs at block-contiguous slots
  for (int k = 0; k < RADIX_UNITS / 256; ++k) {
    int u = u0 + k * 256 + tid;
    if (u < nunits) {
      long long apk = ((const long long*)ra)[u];
      long long bpk = ((const long long*)rb)[u];
      int a0 = (int)apk, a1 = (int)(apk >> 32);
      int b0 = (int)bpk, b1 = (int)(bpk >> 32);
      bool has1 = (2 * u + 1) < nedges;
      int d[4], s[4];
      d[0] = a0; s[0] = b0;
      d[1] = b0; s[1] = a0;
      d[2] = has1 ? a1 : -1; s[2] = b1;
      d[3] = has1 ? b1 : -1; s[3] = a1;
#pragma unroll
      for (int i = 0; i < 4; ++i) {
        if (d[i] >= 0) {
          int b = d[i] >> 7;
          int slot = atomicAdd(&lh[b], 1);
          if (slot < BCAP) binned[(size_t)b * BCAP + slot] = make_int2(d[i], s[i]);
        }
      }
    }
  }
}

// ---------------------------------------------------------------------------
// K2: bin_build fused into gather (r10-proven structure). Round-11 change:
// single-use streams no longer pollute L2 -- binned pairs read NONTEMPORAL
// (9.6MB, read-once) and xagg rows stored NONTEMPORAL (25MB, not re-read
// in-kernel). Both previously allocated in L2 and evicted hot X rows that
// the random neighbor reads depend on (4MB/XCD vs 25.6MB X working set).
// X row loads stay normal/cached -- they are the reuse.
// ---------------------------------------------------------------------------
__global__ __launch_bounds__(256) void gather_bin_kernel(
    const u16* __restrict__ Xb, const int2* __restrict__ binned,
    const int* __restrict__ gOff, int* __restrict__ xagg, int nnodes) {
  __shared__ int lists[128 * CAP];  // 32 KB
  __shared__ int lc[128];
  const int tid = threadIdx.x;
  const int bin = blockIdx.x;
  if (tid < 128) lc[tid] = 0;
  __syncthreads();
  int count = gOff[bin];
  if (count > BCAP) count = BCAP;
  const long long* src = (const long long*)(binned + (size_t)bin * BCAP);
  for (int i = tid; i < count; i += 256) {
    long long pk = __builtin_nontemporal_load(src + i);
    int dst = (int)pk, val = (int)(pk >> 32);
    int loc = dst & 127;
    int p = atomicAdd(&lc[loc], 1);
    if (p < CAP) lists[loc * CAP + p] = val;
  }
  __syncthreads();

  // gather: 4 waves x 2 half-waves = 8 rows/pass, 16 passes = 128 rows
  const int w = tid >> 6;
  const int l = tid & 63;
  const int half = l >> 5;
  const int hl = l & 31;
  const uint2* Xv = (const uint2*)Xb;  // row = 32 uint2 (256 B)
  for (int p = 0; p < 16; ++p) {
    int lr = p * 8 + w * 2 + half;  // 0..127
    int v = (bin << 7) + lr;
    if (v >= nnodes) continue;
    int n = lc[lr];
    if (n > CAP) n = CAP;
    const int* myl = &lists[lr * CAP];
    uint2 ps = Xv[(size_t)v * 32 + hl];
    float a0 = __uint_as_float(ps.x << 16);
    float a1 = __uint_as_float(ps.x & 0xffff0000u);
    float a2 = __uint_as_float(ps.y << 16);
    float a3 = __uint_as_float(ps.y & 0xffff0000u);
    for (int k = 0; k < n; k += 8) {
      uint2 pv[8];
#pragma unroll
      for (int t = 0; t < 8; ++t) {
        int pos = k + t;    // pos <= 63 always (n <= 64)
        int nb = myl[pos];  // LDS broadcast, uniform across half-wave
        pv[t] = (pos < n) ? Xv[(size_t)nb * 32 + hl] : make_uint2(0u, 0u);
      }
#pragma unroll
      for (int t = 0; t < 8; ++t) {
        a0 += __uint_as_float(pv[t].x << 16);
        a1 += __uint_as_float(pv[t].x & 0xffff0000u);
        a2 += __uint_as_float(pv[t].y << 16);
        a3 += __uint_as_float(pv[t].y & 0xffff0000u);
      }
    }
    u32x2 o;
    o[0] = (u32)f32_to_bf16(a0) | ((u32)f32_to_bf16(a1) << 16);
    o[1] = (u32)f32_to_bf16(a2) | ((u32)f32_to_bf16(a3) << 16);
    __builtin_nontemporal_store(
        o, (u32x2*)((uint2*)xagg + (size_t)v * 32 + hl));
  }
}

// ---------------------------------------------------------------------------
// K4: fused MLP via bf16 MFMA (16x16x32) -- r4-proven; round-11: `out`
// stores nontemporal (51.2MB, never re-read -> skip L2 write-allocate).
// ---------------------------------------------------------------------------
__global__ __launch_bounds__(256) void mlp_mfma_kernel(
    const u16* __restrict__ Xagg,  // [nnodes][128] bf16 (ws region)
    const u16* __restrict__ WhT,   // [128][128] bf16, [n][k]
    const u16* __restrict__ WoT,   // [128][128] bf16, [n][k]
    const float* __restrict__ bh,
    const float* __restrict__ bo,
    float* __restrict__ out, int nnodes) {
  __shared__ u16 smem[2 * 128 * 128];  // 64 KB
  u16* sA = smem;
  u16* sW = smem + 16384;

  const int tid = threadIdx.x;
  const int w = tid >> 6;
  const int l = tid & 63;
  const int l15 = l & 15;
  const int l4 = l >> 4;  // quad 0..3
  const int r0 = blockIdx.x * 128;

  // ---- stage sA (Xagg tile) and sW (Wh^T), swizzled 16B units ----
#pragma unroll
  for (int t = 0; t < 8; ++t) {
    int id = tid + t * 256;  // 0..2047 : 128 rows x 16 units
    int r = id >> 4, u = id & 15;
    int gr = r0 + r;
    if (gr >= nnodes) gr = nnodes - 1;
    *(int4*)&sA[r * 128 + ((u ^ (r & 15)) * 8)] =
        *(const int4*)&Xagg[(size_t)gr * 128 + u * 8];
    *(int4*)&sW[r * 128 + ((u ^ (r & 15)) * 8)] =
        *(const int4*)&WhT[r * 128 + u * 8];
  }

  float bhv[8], bov[8];
#pragma unroll
  for (int j = 0; j < 8; ++j) {
    bhv[j] = bh[j * 16 + l15];
    bov[j] = bo[j * 16 + l15];
  }
  __syncthreads();

  const int m0 = w * 32 + l15;       // A row, m-tile 0
  const int m1 = w * 32 + 16 + l15;  // A row, m-tile 1

  f32x4 acc[2][8];
#pragma unroll
  for (int i = 0; i < 2; ++i)
#pragma unroll
    for (int j = 0; j < 8; ++j) acc[i][j] = (f32x4){0.f, 0.f, 0.f, 0.f};

  // ---- GEMM1: hidden = Xagg @ Wh ----
#pragma unroll
  for (int c = 0; c < 4; ++c) {  // K chunks of 32
    int pu = ((c * 4 + l4) ^ l15) * 8;
    bf16x8 a0 = *(bf16x8*)&sA[m0 * 128 + pu];
    bf16x8 a1 = *(bf16x8*)&sA[m1 * 128 + pu];
#pragma unroll
    for (int j = 0; j < 8; ++j) {
      bf16x8 bfr = *(bf16x8*)&sW[(j * 16 + l15) * 128 + pu];
      acc[0][j] = __builtin_amdgcn_mfma_f32_16x16x32_bf16(a0, bfr, acc[0][j], 0, 0, 0);
      acc[1][j] = __builtin_amdgcn_mfma_f32_16x16x32_bf16(a1, bfr, acc[1][j], 0, 0, 0);
    }
  }

  __syncthreads();  // all waves done reading sW (GEMM1)

  // ---- restage sW with Wo^T ----
#pragma unroll
  for (int t = 0; t < 8; ++t) {
    int id = tid + t * 256;
    int r = id >> 4, u = id & 15;
    *(int4*)&sW[r * 128 + ((u ^ (r & 15)) * 8)] =
        *(const int4*)&WoT[r * 128 + u * 8];
  }

  // ---- bias + relu + bf16, write hidden into sA (own rows only) ----
#pragma unroll
  for (int i = 0; i < 2; ++i)
#pragma unroll
    for (int j = 0; j < 8; ++j)
#pragma unroll
      for (int r = 0; r < 4; ++r) {
        int m = w * 32 + i * 16 + l4 * 4 + r;
        float v = fmaxf(acc[i][j][r] + bhv[j], 0.f);
        int k = j * 16 + l15;
        sA[m * 128 + (((k >> 3) ^ (m & 15)) * 8) + (k & 7)] = f32_to_bf16(v);
      }
  __syncthreads();

  // ---- GEMM2: out = hidden @ Wo (reuse acc) ----
#pragma unroll
  for (int i = 0; i < 2; ++i)
#pragma unroll
    for (int j = 0; j < 8; ++j) acc[i][j] = (f32x4){0.f, 0.f, 0.f, 0.f};

#pragma unroll
  for (int c = 0; c < 4; ++c) {
    int pu = ((c * 4 + l4) ^ l15) * 8;
    bf16x8 a0 = *(bf16x8*)&sA[m0 * 128 + pu];
    bf16x8 a1 = *(bf16x8*)&sA[m1 * 128 + pu];
#pragma unroll
    for (int j = 0; j < 8; ++j) {
      bf16x8 bfr = *(bf16x8*)&sW[(j * 16 + l15) * 128 + pu];
      acc[0][j] = __builtin_amdgcn_mfma_f32_16x16x32_bf16(a0, bfr, acc[0][j], 0, 0, 0);
      acc[1][j] = __builtin_amdgcn_mfma_f32_16x16x32_bf16(a1, bfr, acc[1][j], 0, 0, 0);
    }
  }

  __syncthreads();  // everyone done with sA/sW -> reuse as fp32 out stage

  // ---- epilogue: + bo, stage in LDS, coalesced nontemporal dwordx4 ----
  float* sOut = (float*)smem;  // 128 x 128 fp32 = 64 KB
#pragma unroll
  for (int i = 0; i < 2; ++i)
#pragma unroll
    for (int j = 0; j < 8; ++j)
#pragma unroll
      for (int r = 0; r < 4; ++r) {
        int m = w * 32 + i * 16 + l4 * 4 + r;
        sOut[m * 128 + j * 16 + l15] = acc[i][j][r] + bov[j];
      }
  __syncthreads();
#pragma unroll
  for (int t = 0; t < 16; ++t) {
    int id = tid + t * 256;  // 0..4095 float4 units
    int r = id >> 5, u4 = id & 31;
    int gr = r0 + r;
    if (gr < nnodes) {
      f32x4 val = *(const f32x4*)&sOut[id * 4];
      __builtin_nontemporal_store(val, (f32x4*)out + (size_t)gr * 32 + u4);
    }
  }
}

// ---------------------------------------------------------------------------
extern "C" void kernel_launch(void* const* d_in, const int* in_sizes, int n_in,
                              void* d_out, int out_size, void* d_ws,
                              size_t ws_size, hipStream_t stream) {
  const float* X = (const float*)d_in[0];
  const int* ra = (const int*)d_in[1];
  const int* rb = (const int*)d_in[2];
  const float* Wh = (const float*)d_in[3];
  const float* bh = (const float*)d_in[4];
  const float* Wo = (const float*)d_in[5];
  const float* bo = (const float*)d_in[6];
  float* out = (float*)d_out;

  int nnodes = in_sizes[0] / 128;
  int nedges = in_sizes[1];
  int nunits = (nedges + 1) / 2;         // int2 edge units
  int nbins = (nnodes + 127) >> 7;       // 128-node FINE bins (782)
  int nradix = (nunits + RADIX_UNITS - 1) / RADIX_UNITS;

  // ws layout (r9/r10-proven): [head 400KB: WhT/WoT | xagg @ byte nnodes*4].
  u16* WhT = (u16*)d_ws;
  u16* WoT = WhT + 16384;
  int* xagg = (int*)d_ws + nnodes;

  // d_out transient layout: [Xb: nnodes*256B | binned: nbins*BCAP*8 | gOff]
  // (binned/gOff dead before mlp writes out; Xb consumed by gather).
  u16* Xb = (u16*)d_out;
  int2* binned = (int2*)((char*)d_out + (size_t)nnodes * 256);
  int* gOff = (int*)((char*)binned + (size_t)nbins * BCAP * sizeof(int2));

  int n8 = nnodes * 16;  // 128 feats / 8 per thread
  int nconv = (n8 + 255) / 256;
  (void)hipMemsetAsync(gOff, 0, (size_t)nbins * 4, stream);
  front_kernel<<<nradix + nconv + 128, 256, 0, stream>>>(
      X, Xb, n8, ra, rb, gOff, binned, Wh, Wo, WhT, WoT, nedges, nunits,
      nbins, nradix, nconv);
  gather_bin_kernel<<<nbins, 256, 0, stream>>>(Xb, binned, gOff, xagg,
                                               nnodes);
  mlp_mfma_kernel<<<(nnodes + 127) / 128, 256, 0, stream>>>(
      (const u16*)xagg, WhT, WoT, bh, bo, out, nnodes);
}